// Round 6
// baseline (17643.413 us; speedup 1.0000x reference)
//
#include <hip/hip_runtime.h>
#include <hip/hip_bf16.h>
#include <math.h>

#define NN 8192
#define DD 256
#define HH 128
#define RPB 16
#define DT_F 0.01f
#define TWO_PI_F 6.28318530717958647692f
#define ROWB 12288   // packed bytes per row: 8192 low-byte + 4096 high-nibble
#define NBLK 256     // persistent grid = CU count

__device__ __forceinline__ float gelu_exact(float t) {
    return 0.5f * t * (1.f + erff(t * 0.70710678118654752440f));
}
__device__ __forceinline__ float sigmoidf(float t) {
    return 1.f / (1.f + expf(-t));
}

// 12-bit unpack + accumulate: 4 elements of one lo-word (round 3/4 verified)
__device__ __forceinline__ void acc4(unsigned lo, unsigned he, unsigned ho, const int j0,
                                     float4 cv, float4 sv, float& ac, float& as) {
#if __has_builtin(__builtin_amdgcn_perm)
    unsigned u0 = __builtin_amdgcn_perm(he, lo, 0x0C0C0000u | ((4u + j0) << 8) | 0u);
    unsigned u1 = __builtin_amdgcn_perm(ho, lo, 0x0C0C0000u | ((4u + j0) << 8) | 1u);
    unsigned u2 = __builtin_amdgcn_perm(he, lo, 0x0C0C0000u | ((5u + j0) << 8) | 2u);
    unsigned u3 = __builtin_amdgcn_perm(ho, lo, 0x0C0C0000u | ((5u + j0) << 8) | 3u);
#else
    unsigned u0 = ((lo >> 0)  & 0xFFu) | (((he >> (8 * (j0 / 2))) & 0xFFu) << 8);
    unsigned u1 = ((lo >> 8)  & 0xFFu) | (((ho >> (8 * (j0 / 2))) & 0xFFu) << 8);
    unsigned u2 = ((lo >> 16) & 0xFFu) | (((he >> (8 * (j0 / 2) + 8)) & 0xFFu) << 8);
    unsigned u3 = ((lo >> 24) & 0xFFu) | (((ho >> (8 * (j0 / 2) + 8)) & 0xFFu) << 8);
#endif
    float f0 = (float)u0, f1 = (float)u1, f2 = (float)u2, f3 = (float)u3;
    ac = fmaf(f0, cv.x, ac); as = fmaf(f0, sv.x, as);
    ac = fmaf(f1, cv.y, ac); as = fmaf(f1, sv.y, as);
    ac = fmaf(f2, cv.z, ac); as = fmaf(f2, sv.z, as);
    ac = fmaf(f3, cv.w, ac); as = fmaf(f3, sv.w, as);
}

// ---------------- A fp32 -> packed 12-bit (round 4 layout, verbatim) --------
// group g = it*64 + lane (512 groups of 16 elements per row),
// element(it,lane,j,m) = 4*lane + 1024*it + 256*j + m   (j,m in 0..3)
__global__ __launch_bounds__(512) void convert_pack_kernel(
    const float* __restrict__ A, unsigned char* __restrict__ Ap)
{
    const int row = blockIdx.x;
    const int g = threadIdx.x;
    const int lane = g & 63, itq = g >> 6;
    const float* src = A + (size_t)row * NN + 4 * lane + 1024 * itq;
    unsigned q[16];
#pragma unroll
    for (int j = 0; j < 4; ++j) {
        float4 f = *(const float4*)(src + 256 * j);
        float v[4] = {f.x, f.y, f.z, f.w};
#pragma unroll
        for (int m = 0; m < 4; ++m) {
            float c = fminf(fmaxf(v[m], 0.f), 1.f);
            q[4 * j + m] = (unsigned)__float2int_rn(c * 4095.f);
        }
    }
    uint4 lo;
    lo.x = (q[0] & 0xFF) | ((q[1] & 0xFF) << 8) | ((q[2] & 0xFF) << 16) | ((q[3] & 0xFF) << 24);
    lo.y = (q[4] & 0xFF) | ((q[5] & 0xFF) << 8) | ((q[6] & 0xFF) << 16) | ((q[7] & 0xFF) << 24);
    lo.z = (q[8] & 0xFF) | ((q[9] & 0xFF) << 8) | ((q[10] & 0xFF) << 16) | ((q[11] & 0xFF) << 24);
    lo.w = (q[12] & 0xFF) | ((q[13] & 0xFF) << 8) | ((q[14] & 0xFF) << 16) | ((q[15] & 0xFF) << 24);
    uint2 nb;
    nb.x = (q[0] >> 8) | ((q[1] >> 8) << 4) | ((q[2] >> 8) << 8) | ((q[3] >> 8) << 12)
         | ((q[4] >> 8) << 16) | ((q[5] >> 8) << 20) | ((q[6] >> 8) << 24) | ((q[7] >> 8) << 28);
    nb.y = (q[8] >> 8) | ((q[9] >> 8) << 4) | ((q[10] >> 8) << 8) | ((q[11] >> 8) << 12)
         | ((q[12] >> 8) << 16) | ((q[13] >> 8) << 20) | ((q[14] >> 8) << 24) | ((q[15] >> 8) << 28);
    unsigned char* rowp = Ap + (size_t)row * ROWB;
    ((uint4*)rowp)[g] = lo;
    ((uint2*)(rowp + 8192))[g] = nb;
}

// ---------------- pre: frequencies, coupling, phases0, cos/sin snapshot ----
__global__ __launch_bounds__(256) void pre_kernel(
    const float* __restrict__ x,
    const float* __restrict__ fw1, const float* __restrict__ fb1,
    const float* __restrict__ flng, const float* __restrict__ flnb,
    const float* __restrict__ fw2, const float* __restrict__ fb2,
    const float* __restrict__ fw3, const float* __restrict__ fb3,
    const float* __restrict__ cw1, const float* __restrict__ cb1,
    const float* __restrict__ cw2, const float* __restrict__ cb2,
    const float* __restrict__ gcp,
    float* __restrict__ freq_out, float* __restrict__ coup_out,
    float* __restrict__ cs_ws, float* __restrict__ phases_out,
    float* __restrict__ pc0f, float* __restrict__ ps0f)
{
    __shared__ float xs[RPB][DD];
    __shared__ float h1[RPB][DD];
    __shared__ float h2[RPB][HH];
    __shared__ float hc[RPB][HH];
    const int tid = threadIdx.x;
    const int base_row = blockIdx.x * RPB;

    {
        const float4* xg = (const float4*)(x + (size_t)base_row * DD);
        float4* xv = (float4*)&xs[0][0];
        for (int i = tid; i < RPB * DD / 4; i += 256) xv[i] = xg[i];
    }
    __syncthreads();

    {
        float acc[RPB];
#pragma unroll
        for (int r = 0; r < RPB; ++r) acc[r] = 0.f;
        const int c = tid;
        for (int k = 0; k < DD; k += 4) {
            float w0 = fw1[(k + 0) * DD + c];
            float w1 = fw1[(k + 1) * DD + c];
            float w2 = fw1[(k + 2) * DD + c];
            float w3 = fw1[(k + 3) * DD + c];
#pragma unroll
            for (int r = 0; r < RPB; ++r) {
                float4 xv = *(const float4*)&xs[r][k];
                acc[r] += xv.x * w0 + xv.y * w1 + xv.z * w2 + xv.w * w3;
            }
        }
        float bb = fb1[c];
#pragma unroll
        for (int r = 0; r < RPB; ++r) h1[r][c] = acc[r] + bb;
    }
    __syncthreads();

    {
        const int wave = tid >> 6, lane = tid & 63;
        for (int r = wave; r < RPB; r += 4) {
            float v0 = h1[r][lane], v1 = h1[r][lane + 64], v2 = h1[r][lane + 128], v3 = h1[r][lane + 192];
            float s = v0 + v1 + v2 + v3;
            for (int off = 32; off; off >>= 1) s += __shfl_xor(s, off);
            float m = s * (1.f / DD);
            float d0 = v0 - m, d1 = v1 - m, d2 = v2 - m, d3 = v3 - m;
            float q = d0 * d0 + d1 * d1 + d2 * d2 + d3 * d3;
            for (int off = 32; off; off >>= 1) q += __shfl_xor(q, off);
            float rstd = rsqrtf(q * (1.f / DD) + 1e-5f);
            h1[r][lane]       = tanhf(d0 * rstd * flng[lane]       + flnb[lane]);
            h1[r][lane + 64]  = tanhf(d1 * rstd * flng[lane + 64]  + flnb[lane + 64]);
            h1[r][lane + 128] = tanhf(d2 * rstd * flng[lane + 128] + flnb[lane + 128]);
            h1[r][lane + 192] = tanhf(d3 * rstd * flng[lane + 192] + flnb[lane + 192]);
        }
    }
    __syncthreads();

    if (tid < HH) {
        const int c = tid;
        float acc[RPB];
#pragma unroll
        for (int r = 0; r < RPB; ++r) acc[r] = 0.f;
        for (int k = 0; k < DD; k += 4) {
            float w0 = fw2[(k + 0) * HH + c];
            float w1 = fw2[(k + 1) * HH + c];
            float w2 = fw2[(k + 2) * HH + c];
            float w3 = fw2[(k + 3) * HH + c];
#pragma unroll
            for (int r = 0; r < RPB; ++r) {
                float4 xv = *(const float4*)&h1[r][k];
                acc[r] += xv.x * w0 + xv.y * w1 + xv.z * w2 + xv.w * w3;
            }
        }
        float bb = fb2[c];
#pragma unroll
        for (int r = 0; r < RPB; ++r) h2[r][c] = tanhf(acc[r] + bb);
    } else {
        const int c = tid - HH;
        float acc[RPB];
#pragma unroll
        for (int r = 0; r < RPB; ++r) acc[r] = 0.f;
        for (int k = 0; k < DD; k += 4) {
            float w0 = cw1[(k + 0) * HH + c];
            float w1 = cw1[(k + 1) * HH + c];
            float w2 = cw1[(k + 2) * HH + c];
            float w3 = cw1[(k + 3) * HH + c];
#pragma unroll
            for (int r = 0; r < RPB; ++r) {
                float4 xv = *(const float4*)&xs[r][k];
                acc[r] += xv.x * w0 + xv.y * w1 + xv.z * w2 + xv.w * w3;
            }
        }
        float bb = cb1[c];
#pragma unroll
        for (int r = 0; r < RPB; ++r) {
            float t = acc[r] + bb;
            hc[r][c] = gelu_exact(t);
        }
    }
    __syncthreads();

    {
        const int wave = tid >> 6, lane = tid & 63;
        float gc = fminf(fmaxf(gcp[0], 0.1f), 2.0f);
        for (int r = wave; r < RPB; r += 4) {
            float f = h2[r][lane] * fw3[lane] + h2[r][lane + 64] * fw3[lane + 64];
            for (int off = 32; off; off >>= 1) f += __shfl_xor(f, off);
            float cpl = hc[r][lane] * cw2[lane] + hc[r][lane + 64] * cw2[lane + 64];
            for (int off = 32; off; off >>= 1) cpl += __shfl_xor(cpl, off);
            float ssum = 0.f, csum = 0.f;
#pragma unroll
            for (int j = 0; j < 4; ++j) {
                int idx = lane + 64 * j;
                float xv = xs[r][idx];
                float fi = (float)idx;
                ssum += xv * sinf(fi);
                csum += xv * cosf(fi);
            }
            for (int off = 32; off; off >>= 1) {
                ssum += __shfl_xor(ssum, off);
                csum += __shfl_xor(csum, off);
            }
            if (lane == 0) {
                int row = base_row + r;
                freq_out[row] = f + fb3[0];
                float sg = sigmoidf(cpl + cb2[0]);
                coup_out[row] = sg;
                cs_ws[row] = sg * gc;
                float ph = atan2f(ssum, csum);
                phases_out[row] = ph;
                pc0f[row] = cosf(ph);
                ps0f[row] = sinf(ph);
            }
        }
    }
}

// ---------------- device-scope grid barrier (gen INSIDE zeroed region) ------
__device__ __forceinline__ void gbar(unsigned* cnt, unsigned* gen, unsigned* mygen) {
    __syncthreads();
    if (threadIdx.x == 0) {
        unsigned arrived = __hip_atomic_fetch_add(cnt, 1u, __ATOMIC_ACQ_REL, __HIP_MEMORY_SCOPE_AGENT);
        if (arrived == NBLK - 1u) {
            __hip_atomic_store(cnt, 0u, __ATOMIC_RELAXED, __HIP_MEMORY_SCOPE_AGENT);
            __hip_atomic_fetch_add(gen, 1u, __ATOMIC_ACQ_REL, __HIP_MEMORY_SCOPE_AGENT);
        } else {
            while (__hip_atomic_load(gen, __ATOMIC_ACQUIRE, __HIP_MEMORY_SCOPE_AGENT) == *mygen)
                __builtin_amdgcn_s_sleep(2);
        }
        *mygen += 1u;
    }
    __syncthreads();
}

// ---------------- persistent Kuramoto: A in registers, 60 steps -------------
// Wave w of block b owns 4 FULL rows 32b+4w..+3; per-row accumulation order is
// bitwise-identical to round 4's step_kernel_p (same convert layout, same acc4
// sequence, same butterfly), so the trajectory replicates the passing kernel.
__global__ __launch_bounds__(512, 2) void kuramoto_kernel(
    const unsigned char* __restrict__ Ap, const float* __restrict__ freq,
    const float* __restrict__ csv, float* __restrict__ phases,
    float* __restrict__ vA, float* __restrict__ vB,
    unsigned* __restrict__ bar)
{
    __shared__ float vc[NN];        // 32 KB cos
    __shared__ float vs[NN];        // 32 KB sin
    __shared__ float part[8][8];
    const int tid = threadIdx.x, l = tid & 63, w = tid >> 6;
    const int b = blockIdx.x;

    // ---- load this lane's A tile into registers (192 VGPRs) ----
    uint4 ulo[4][8];
    uint2 unb[4][8];
#pragma unroll
    for (int r = 0; r < 4; ++r) {
        const int R = 32 * b + 4 * w + r;
        const uint4* lop = (const uint4*)(Ap + (size_t)R * ROWB);
        const uint2* nbp = (const uint2*)(Ap + (size_t)R * ROWB + 8192);
#pragma unroll
        for (int it = 0; it < 8; ++it) {
            ulo[r][it] = lop[it * 64 + l];
            unb[r][it] = nbp[it * 64 + l];
        }
    }
    float myphase = 0.f, myfreq = 0.f, mycs = 0.f;
    if (tid < 32) {
        int R = 32 * b + tid;
        myphase = phases[R];
        myfreq = freq[R];
        mycs = csv[R];
    }
    unsigned mygen = 0;

    for (int t = 0; t < 60; ++t) {
        const float* vin = (t & 1) ? vB : vA;
        float* vout = (t & 1) ? vA : vB;
        const unsigned long long* vin8 = (const unsigned long long*)vin;
        // ---- stage cos/sin (16384 f32) to LDS via LLC-coherent loads ----
#pragma unroll
        for (int k = 0; k < 8; ++k) {
            int c4 = tid + 512 * k;   // float4 chunk 0..4095
            unsigned long long d0 = __hip_atomic_load(vin8 + 2 * c4,     __ATOMIC_RELAXED, __HIP_MEMORY_SCOPE_AGENT);
            unsigned long long d1 = __hip_atomic_load(vin8 + 2 * c4 + 1, __ATOMIC_RELAXED, __HIP_MEMORY_SCOPE_AGENT);
            int fi = c4 * 4;
            float* dst = (fi < NN) ? (vc + fi) : (vs + (fi - NN));
            ((unsigned long long*)dst)[0] = d0;
            ((unsigned long long*)dst)[1] = d1;
        }
        __syncthreads();
        // ---- dot products: 4 full rows per wave, round-4 element order ----
        float lac[4], las[4];
#pragma unroll
        for (int r = 0; r < 4; ++r) { lac[r] = 0.f; las[r] = 0.f; }
        const float4* Pc = (const float4*)vc;
        const float4* Ps = (const float4*)vs;
#pragma unroll
        for (int it = 0; it < 8; ++it) {
            const int base = l + 256 * it;
            float4 c0 = Pc[base], c1 = Pc[base + 64], c2 = Pc[base + 128], c3 = Pc[base + 192];
            float4 s0 = Ps[base], s1 = Ps[base + 64], s2 = Ps[base + 128], s3 = Ps[base + 192];
#pragma unroll
            for (int r = 0; r < 4; ++r) {
                uint4 lo = ulo[r][it];
                uint2 nb = unb[r][it];
                unsigned hea = nb.x & 0x0F0F0F0Fu, hoa = (nb.x >> 4) & 0x0F0F0F0Fu;
                unsigned heb = nb.y & 0x0F0F0F0Fu, hob = (nb.y >> 4) & 0x0F0F0F0Fu;
                acc4(lo.x, hea, hoa, 0, c0, s0, lac[r], las[r]);
                acc4(lo.y, hea, hoa, 2, c1, s1, lac[r], las[r]);
                acc4(lo.z, heb, hob, 0, c2, s2, lac[r], las[r]);
                acc4(lo.w, heb, hob, 2, c3, s3, lac[r], las[r]);
            }
        }
        // ---- wave butterfly (round-4 order), publish per-row sums ----
#pragma unroll
        for (int r = 0; r < 4; ++r) {
            float c = lac[r], s = las[r];
            for (int off = 32; off; off >>= 1) { c += __shfl_xor(c, off); s += __shfl_xor(s, off); }
            if (l == 0) { part[w][2 * r] = c; part[w][2 * r + 1] = s; }
        }
        __syncthreads();
        // ---- phase update: tid<32, row 32b+tid (wave tid>>2, row tid&3) ----
        if (tid < 32) {
            const float inv = 1.f / 4095.f;
            float c = part[tid >> 2][2 * (tid & 3)] * inv;
            float s = part[tid >> 2][2 * (tid & 3) + 1] * inv;
            float ce = atan2f(s, c + 1e-8f) - myphase;
            float dphi = myfreq + mycs * sinf(ce);
            float pn = myphase + DT_F * dphi;
            pn = fmodf(pn, TWO_PI_F);
            if (pn < 0.f) pn += TWO_PI_F;
            myphase = pn;
            if (t < 59) {
                int R = 32 * b + tid;
                __hip_atomic_store(vout + R,      cosf(pn), __ATOMIC_RELAXED, __HIP_MEMORY_SCOPE_AGENT);
                __hip_atomic_store(vout + NN + R, sinf(pn), __ATOMIC_RELAXED, __HIP_MEMORY_SCOPE_AGENT);
            }
        }
        if (t < 59) gbar(bar, bar + 32, &mygen);
    }
    if (tid < 32) phases[32 * b + tid] = myphase;
}

// ---------------- fp32 fallback step (ws too small) -------------------------
#define FSROWS 8
#define CHUNK 4096
__global__ __launch_bounds__(256) void step_kernel(
    const float* __restrict__ A,
    const float* __restrict__ pc_in, const float* __restrict__ ps_in,
    const float* __restrict__ freq, const float* __restrict__ cs,
    float* __restrict__ phases,
    float* __restrict__ pc_out, float* __restrict__ ps_out)
{
    __shared__ float pcs[CHUNK];
    __shared__ float pss[CHUNK];
    const int tid = threadIdx.x, lane = tid & 63, wave = tid >> 6;
    const int row0 = blockIdx.x * FSROWS + wave * (FSROWS / 4);
    float accC[FSROWS / 4], accS[FSROWS / 4];
#pragma unroll
    for (int rr = 0; rr < FSROWS / 4; ++rr) { accC[rr] = 0.f; accS[rr] = 0.f; }
    for (int ch = 0; ch < NN / CHUNK; ++ch) {
        const float4* pcg = (const float4*)(pc_in + ch * CHUNK);
        const float4* psg = (const float4*)(ps_in + ch * CHUNK);
        for (int i = tid; i < CHUNK / 4; i += 256) {
            ((float4*)pcs)[i] = pcg[i];
            ((float4*)pss)[i] = psg[i];
        }
        __syncthreads();
#pragma unroll
        for (int rr = 0; rr < FSROWS / 4; ++rr) {
            const float4* Ar = (const float4*)(A + (size_t)(row0 + rr) * NN + ch * CHUNK);
            float lac = 0.f, las = 0.f;
#pragma unroll 4
            for (int it = 0; it < CHUNK / 256; ++it) {
                int c4 = it * 64 + lane;
                float4 a = Ar[c4];
                float4 c = ((const float4*)pcs)[c4];
                float4 s = ((const float4*)pss)[c4];
                lac += a.x * c.x + a.y * c.y + a.z * c.z + a.w * c.w;
                las += a.x * s.x + a.y * s.y + a.z * s.z + a.w * s.w;
            }
            accC[rr] += lac;
            accS[rr] += las;
        }
        __syncthreads();
    }
#pragma unroll
    for (int rr = 0; rr < FSROWS / 4; ++rr) {
        float c = accC[rr], s = accS[rr];
        for (int off = 32; off; off >>= 1) {
            c += __shfl_xor(c, off);
            s += __shfl_xor(s, off);
        }
        if (lane == 0) {
            int row = row0 + rr;
            float ph = phases[row];
            float ce = atan2f(s, c + 1e-8f) - ph;
            float dphi = freq[row] + cs[row] * sinf(ce);
            float pn = fmodf(ph + DT_F * dphi, TWO_PI_F);
            if (pn < 0.f) pn += TWO_PI_F;
            phases[row] = pn;
            pc_out[row] = cosf(pn);
            ps_out[row] = sinf(pn);
        }
    }
}

// ---------------- post: sync_input, sync MLP -> desync ----------------------
#define SD 260
#define SDP 264
__global__ __launch_bounds__(256) void post_kernel(
    const float* __restrict__ x, const float* __restrict__ phases,
    const float* __restrict__ sw1, const float* __restrict__ sb1,
    const float* __restrict__ slng, const float* __restrict__ slnb,
    const float* __restrict__ sw2, const float* __restrict__ sb2,
    const float* __restrict__ sw3, const float* __restrict__ sb3,
    float* __restrict__ sync_out, float* __restrict__ desync_out)
{
    __shared__ float xs[RPB][SDP];
    __shared__ float h1[RPB][DD];
    __shared__ float h2[RPB][HH];
    const int tid = threadIdx.x;
    const int base_row = blockIdx.x * RPB;

    for (int i = tid; i < RPB * DD / 4; i += 256) {
        int r = i / (DD / 4), c4 = i % (DD / 4);
        *(float4*)&xs[r][c4 * 4] = ((const float4*)(x + (size_t)(base_row + r) * DD))[c4];
    }
    if (tid < RPB) {
        float p = phases[base_row + tid];
        xs[tid][256] = cosf(p);
        xs[tid][257] = sinf(p);
        xs[tid][258] = cosf(2.f * p);
        xs[tid][259] = sinf(2.f * p);
    }
    __syncthreads();

    for (int i = tid; i < RPB * SD; i += 256) {
        int r = i / SD, c = i % SD;
        sync_out[(size_t)(base_row + r) * SD + c] = xs[r][c];
    }

    {
        float acc[RPB];
#pragma unroll
        for (int r = 0; r < RPB; ++r) acc[r] = 0.f;
        const int c = tid;
        for (int k = 0; k < SD; k += 4) {
            float w0 = sw1[(k + 0) * DD + c];
            float w1 = sw1[(k + 1) * DD + c];
            float w2 = sw1[(k + 2) * DD + c];
            float w3 = sw1[(k + 3) * DD + c];
#pragma unroll
            for (int r = 0; r < RPB; ++r) {
                float4 xv = *(const float4*)&xs[r][k];
                acc[r] += xv.x * w0 + xv.y * w1 + xv.z * w2 + xv.w * w3;
            }
        }
        float bb = sb1[c];
#pragma unroll
        for (int r = 0; r < RPB; ++r) h1[r][c] = acc[r] + bb;
    }
    __syncthreads();

    {
        const int wave = tid >> 6, lane = tid & 63;
        for (int r = wave; r < RPB; r += 4) {
            float v0 = h1[r][lane], v1 = h1[r][lane + 64], v2 = h1[r][lane + 128], v3 = h1[r][lane + 192];
            float s = v0 + v1 + v2 + v3;
            for (int off = 32; off; off >>= 1) s += __shfl_xor(s, off);
            float m = s * (1.f / DD);
            float d0 = v0 - m, d1 = v1 - m, d2 = v2 - m, d3 = v3 - m;
            float q = d0 * d0 + d1 * d1 + d2 * d2 + d3 * d3;
            for (int off = 32; off; off >>= 1) q += __shfl_xor(q, off);
            float rstd = rsqrtf(q * (1.f / DD) + 1e-5f);
            h1[r][lane]       = gelu_exact(d0 * rstd * slng[lane]       + slnb[lane]);
            h1[r][lane + 64]  = gelu_exact(d1 * rstd * slng[lane + 64]  + slnb[lane + 64]);
            h1[r][lane + 128] = gelu_exact(d2 * rstd * slng[lane + 128] + slnb[lane + 128]);
            h1[r][lane + 192] = gelu_exact(d3 * rstd * slng[lane + 192] + slnb[lane + 192]);
        }
    }
    __syncthreads();

    if (tid < HH) {
        const int c = tid;
        float acc[RPB];
#pragma unroll
        for (int r = 0; r < RPB; ++r) acc[r] = 0.f;
        for (int k = 0; k < DD; k += 4) {
            float w0 = sw2[(k + 0) * HH + c];
            float w1 = sw2[(k + 1) * HH + c];
            float w2 = sw2[(k + 2) * HH + c];
            float w3 = sw2[(k + 3) * HH + c];
#pragma unroll
            for (int r = 0; r < RPB; ++r) {
                float4 xv = *(const float4*)&h1[r][k];
                acc[r] += xv.x * w0 + xv.y * w1 + xv.z * w2 + xv.w * w3;
            }
        }
        float bb = sb2[c];
#pragma unroll
        for (int r = 0; r < RPB; ++r) h2[r][c] = gelu_exact(acc[r] + bb);
    }
    __syncthreads();

    {
        const int wave = tid >> 6, lane = tid & 63;
        for (int r = wave; r < RPB; r += 4) {
            float t = h2[r][lane] * sw3[lane] + h2[r][lane + 64] * sw3[lane + 64];
            for (int off = 32; off; off >>= 1) t += __shfl_xor(t, off);
            if (lane == 0) desync_out[base_row + r] = sigmoidf(t + sb3[0]);
        }
    }
}

// ---------------- global scalar reductions ---------------------------------
__global__ __launch_bounds__(1024) void reduce_kernel(
    const float* __restrict__ phases,
    float* __restrict__ order_out, float* __restrict__ coh_out)
{
    __shared__ double red[16][4];
    const int tid = threadIdx.x;
    double sc = 0, ss = 0, sp = 0, spp = 0;
    for (int i = tid; i < NN; i += 1024) {
        float p = phases[i];
        sc += (double)cosf(p);
        ss += (double)sinf(p);
        sp += (double)p;
        spp += (double)p * (double)p;
    }
    const int lane = tid & 63, wave = tid >> 6;
    for (int off = 32; off; off >>= 1) {
        sc += __shfl_xor(sc, off);
        ss += __shfl_xor(ss, off);
        sp += __shfl_xor(sp, off);
        spp += __shfl_xor(spp, off);
    }
    if (lane == 0) { red[wave][0] = sc; red[wave][1] = ss; red[wave][2] = sp; red[wave][3] = spp; }
    __syncthreads();
    if (tid == 0) {
        sc = 0; ss = 0; sp = 0; spp = 0;
        for (int w = 0; w < 16; ++w) { sc += red[w][0]; ss += red[w][1]; sp += red[w][2]; spp += red[w][3]; }
        double mc = sc / NN, ms = ss / NN;
        order_out[0] = (float)sqrt(mc * mc + ms * ms);
        double var = (spp - sp * sp / NN) / (NN - 1);
        if (var < 0) var = 0;
        coh_out[0] = (float)(1.0 / (1.0 + sqrt(var)));
    }
}

extern "C" void kernel_launch(void* const* d_in, const int* in_sizes, int n_in,
                              void* d_out, int out_size, void* d_ws, size_t ws_size,
                              hipStream_t stream) {
    const float* x    = (const float*)d_in[0];
    const float* A    = (const float*)d_in[1];
    const float* fw1  = (const float*)d_in[2];
    const float* fb1  = (const float*)d_in[3];
    const float* flng = (const float*)d_in[4];
    const float* flnb = (const float*)d_in[5];
    const float* fw2  = (const float*)d_in[6];
    const float* fb2  = (const float*)d_in[7];
    const float* fw3  = (const float*)d_in[8];
    const float* fb3  = (const float*)d_in[9];
    const float* cw1  = (const float*)d_in[10];
    const float* cb1  = (const float*)d_in[11];
    const float* cw2  = (const float*)d_in[12];
    const float* cb2  = (const float*)d_in[13];
    const float* sw1  = (const float*)d_in[14];
    const float* sb1  = (const float*)d_in[15];
    const float* slng = (const float*)d_in[16];
    const float* slnb = (const float*)d_in[17];
    const float* sw2  = (const float*)d_in[18];
    const float* sb2  = (const float*)d_in[19];
    const float* sw3  = (const float*)d_in[20];
    const float* sb3  = (const float*)d_in[21];
    const float* gcp  = (const float*)d_in[22];

    float* out    = (float*)d_out;
    float* desync = out;                    // 8192
    float* order  = out + 8192;             // 1
    float* phases = out + 8193;             // 8192
    float* freqo  = out + 16385;            // 8192
    float* coupo  = out + 24577;            // 8192
    float* synco  = out + 32769;            // 8192*260
    float* coh    = out + 2162689;          // 1

    char* wsb = (char*)d_ws;
    unsigned* bar = (unsigned*)(wsb + 0);        // 512 B, memset each launch
    float* cs  = (float*)(wsb + 4096);           // 32 KB
    float* vA  = (float*)(wsb + 65536);          // 64 KB [cos|sin]
    float* vB  = (float*)(wsb + 131072);         // 64 KB
    unsigned char* Ap = (unsigned char*)(wsb + 262144);  // 96 MiB packed A

    const bool persistent = ws_size >= (size_t)262144 + (size_t)NN * ROWB;

    if (persistent) {
        hipMemsetAsync(bar, 0, 512, stream);
        convert_pack_kernel<<<NN, 512, 0, stream>>>(A, Ap);
    }
    pre_kernel<<<NN / RPB, 256, 0, stream>>>(x, fw1, fb1, flng, flnb, fw2, fb2, fw3, fb3,
                                             cw1, cb1, cw2, cb2, gcp,
                                             freqo, coupo, cs, phases, vA, vA + NN);
    if (persistent) {
        kuramoto_kernel<<<NBLK, 512, 0, stream>>>(Ap, freqo, cs, phases, vA, vB, bar);
    } else {
        for (int t = 0; t < 60; ++t) {
            const float* pin  = (t & 1) ? vB : vA;
            const float* sin_ = (t & 1) ? vB + NN : vA + NN;
            float* pout = (t & 1) ? vA : vB;
            float* sout = (t & 1) ? vA + NN : vB + NN;
            step_kernel<<<NN / FSROWS, 256, 0, stream>>>(A, pin, sin_, freqo, cs, phases, pout, sout);
        }
    }
    post_kernel<<<NN / RPB, 256, 0, stream>>>(x, phases, sw1, sb1, slng, slnb, sw2, sb2, sw3, sb3,
                                              synco, desync);
    reduce_kernel<<<1, 1024, 0, stream>>>(phases, order, coh);
}

// Round 7
// 17538.683 us; speedup vs baseline: 1.0060x; 1.0060x over previous
//
#include <hip/hip_runtime.h>
#include <hip/hip_bf16.h>
#include <math.h>

#define NN 8192
#define DD 256
#define HH 128
#define RPB 16
#define DT_F 0.01f
#define TWO_PI_F 6.28318530717958647692f
#define ROWB 12288   // packed bytes per row: 8192 low-byte + 4096 high-nibble
#define NBLK 256     // persistent grid = CU count

__device__ __forceinline__ float gelu_exact(float t) {
    return 0.5f * t * (1.f + erff(t * 0.70710678118654752440f));
}
__device__ __forceinline__ float sigmoidf(float t) {
    return 1.f / (1.f + expf(-t));
}

// 12-bit unpack + accumulate: 4 elements of one lo-word (round 3/4/6 verified)
__device__ __forceinline__ void acc4(unsigned lo, unsigned he, unsigned ho, const int j0,
                                     float4 cv, float4 sv, float& ac, float& as) {
#if __has_builtin(__builtin_amdgcn_perm)
    unsigned u0 = __builtin_amdgcn_perm(he, lo, 0x0C0C0000u | ((4u + j0) << 8) | 0u);
    unsigned u1 = __builtin_amdgcn_perm(ho, lo, 0x0C0C0000u | ((4u + j0) << 8) | 1u);
    unsigned u2 = __builtin_amdgcn_perm(he, lo, 0x0C0C0000u | ((5u + j0) << 8) | 2u);
    unsigned u3 = __builtin_amdgcn_perm(ho, lo, 0x0C0C0000u | ((5u + j0) << 8) | 3u);
#else
    unsigned u0 = ((lo >> 0)  & 0xFFu) | (((he >> (8 * (j0 / 2))) & 0xFFu) << 8);
    unsigned u1 = ((lo >> 8)  & 0xFFu) | (((ho >> (8 * (j0 / 2))) & 0xFFu) << 8);
    unsigned u2 = ((lo >> 16) & 0xFFu) | (((he >> (8 * (j0 / 2) + 8)) & 0xFFu) << 8);
    unsigned u3 = ((lo >> 24) & 0xFFu) | (((ho >> (8 * (j0 / 2) + 8)) & 0xFFu) << 8);
#endif
    float f0 = (float)u0, f1 = (float)u1, f2 = (float)u2, f3 = (float)u3;
    ac = fmaf(f0, cv.x, ac); as = fmaf(f0, sv.x, as);
    ac = fmaf(f1, cv.y, ac); as = fmaf(f1, sv.y, as);
    ac = fmaf(f2, cv.z, ac); as = fmaf(f2, sv.z, as);
    ac = fmaf(f3, cv.w, ac); as = fmaf(f3, sv.w, as);
}

// ---------------- A fp32 -> packed 12-bit (round 4 layout, verbatim) --------
__global__ __launch_bounds__(512) void convert_pack_kernel(
    const float* __restrict__ A, unsigned char* __restrict__ Ap)
{
    const int row = blockIdx.x;
    const int g = threadIdx.x;
    const int lane = g & 63, itq = g >> 6;
    const float* src = A + (size_t)row * NN + 4 * lane + 1024 * itq;
    unsigned q[16];
#pragma unroll
    for (int j = 0; j < 4; ++j) {
        float4 f = *(const float4*)(src + 256 * j);
        float v[4] = {f.x, f.y, f.z, f.w};
#pragma unroll
        for (int m = 0; m < 4; ++m) {
            float c = fminf(fmaxf(v[m], 0.f), 1.f);
            q[4 * j + m] = (unsigned)__float2int_rn(c * 4095.f);
        }
    }
    uint4 lo;
    lo.x = (q[0] & 0xFF) | ((q[1] & 0xFF) << 8) | ((q[2] & 0xFF) << 16) | ((q[3] & 0xFF) << 24);
    lo.y = (q[4] & 0xFF) | ((q[5] & 0xFF) << 8) | ((q[6] & 0xFF) << 16) | ((q[7] & 0xFF) << 24);
    lo.z = (q[8] & 0xFF) | ((q[9] & 0xFF) << 8) | ((q[10] & 0xFF) << 16) | ((q[11] & 0xFF) << 24);
    lo.w = (q[12] & 0xFF) | ((q[13] & 0xFF) << 8) | ((q[14] & 0xFF) << 16) | ((q[15] & 0xFF) << 24);
    uint2 nb;
    nb.x = (q[0] >> 8) | ((q[1] >> 8) << 4) | ((q[2] >> 8) << 8) | ((q[3] >> 8) << 12)
         | ((q[4] >> 8) << 16) | ((q[5] >> 8) << 20) | ((q[6] >> 8) << 24) | ((q[7] >> 8) << 28);
    nb.y = (q[8] >> 8) | ((q[9] >> 8) << 4) | ((q[10] >> 8) << 8) | ((q[11] >> 8) << 12)
         | ((q[12] >> 8) << 16) | ((q[13] >> 8) << 20) | ((q[14] >> 8) << 24) | ((q[15] >> 8) << 28);
    unsigned char* rowp = Ap + (size_t)row * ROWB;
    ((uint4*)rowp)[g] = lo;
    ((uint2*)(rowp + 8192))[g] = nb;
}

// ---------------- pre: frequencies, coupling, phases0, cos/sin snapshot ----
__global__ __launch_bounds__(256) void pre_kernel(
    const float* __restrict__ x,
    const float* __restrict__ fw1, const float* __restrict__ fb1,
    const float* __restrict__ flng, const float* __restrict__ flnb,
    const float* __restrict__ fw2, const float* __restrict__ fb2,
    const float* __restrict__ fw3, const float* __restrict__ fb3,
    const float* __restrict__ cw1, const float* __restrict__ cb1,
    const float* __restrict__ cw2, const float* __restrict__ cb2,
    const float* __restrict__ gcp,
    float* __restrict__ freq_out, float* __restrict__ coup_out,
    float* __restrict__ cs_ws, float* __restrict__ phases_out,
    float* __restrict__ pc0f, float* __restrict__ ps0f)
{
    __shared__ float xs[RPB][DD];
    __shared__ float h1[RPB][DD];
    __shared__ float h2[RPB][HH];
    __shared__ float hc[RPB][HH];
    const int tid = threadIdx.x;
    const int base_row = blockIdx.x * RPB;

    {
        const float4* xg = (const float4*)(x + (size_t)base_row * DD);
        float4* xv = (float4*)&xs[0][0];
        for (int i = tid; i < RPB * DD / 4; i += 256) xv[i] = xg[i];
    }
    __syncthreads();

    {
        float acc[RPB];
#pragma unroll
        for (int r = 0; r < RPB; ++r) acc[r] = 0.f;
        const int c = tid;
        for (int k = 0; k < DD; k += 4) {
            float w0 = fw1[(k + 0) * DD + c];
            float w1 = fw1[(k + 1) * DD + c];
            float w2 = fw1[(k + 2) * DD + c];
            float w3 = fw1[(k + 3) * DD + c];
#pragma unroll
            for (int r = 0; r < RPB; ++r) {
                float4 xv = *(const float4*)&xs[r][k];
                acc[r] += xv.x * w0 + xv.y * w1 + xv.z * w2 + xv.w * w3;
            }
        }
        float bb = fb1[c];
#pragma unroll
        for (int r = 0; r < RPB; ++r) h1[r][c] = acc[r] + bb;
    }
    __syncthreads();

    {
        const int wave = tid >> 6, lane = tid & 63;
        for (int r = wave; r < RPB; r += 4) {
            float v0 = h1[r][lane], v1 = h1[r][lane + 64], v2 = h1[r][lane + 128], v3 = h1[r][lane + 192];
            float s = v0 + v1 + v2 + v3;
            for (int off = 32; off; off >>= 1) s += __shfl_xor(s, off);
            float m = s * (1.f / DD);
            float d0 = v0 - m, d1 = v1 - m, d2 = v2 - m, d3 = v3 - m;
            float q = d0 * d0 + d1 * d1 + d2 * d2 + d3 * d3;
            for (int off = 32; off; off >>= 1) q += __shfl_xor(q, off);
            float rstd = rsqrtf(q * (1.f / DD) + 1e-5f);
            h1[r][lane]       = tanhf(d0 * rstd * flng[lane]       + flnb[lane]);
            h1[r][lane + 64]  = tanhf(d1 * rstd * flng[lane + 64]  + flnb[lane + 64]);
            h1[r][lane + 128] = tanhf(d2 * rstd * flng[lane + 128] + flnb[lane + 128]);
            h1[r][lane + 192] = tanhf(d3 * rstd * flng[lane + 192] + flnb[lane + 192]);
        }
    }
    __syncthreads();

    if (tid < HH) {
        const int c = tid;
        float acc[RPB];
#pragma unroll
        for (int r = 0; r < RPB; ++r) acc[r] = 0.f;
        for (int k = 0; k < DD; k += 4) {
            float w0 = fw2[(k + 0) * HH + c];
            float w1 = fw2[(k + 1) * HH + c];
            float w2 = fw2[(k + 2) * HH + c];
            float w3 = fw2[(k + 3) * HH + c];
#pragma unroll
            for (int r = 0; r < RPB; ++r) {
                float4 xv = *(const float4*)&h1[r][k];
                acc[r] += xv.x * w0 + xv.y * w1 + xv.z * w2 + xv.w * w3;
            }
        }
        float bb = fb2[c];
#pragma unroll
        for (int r = 0; r < RPB; ++r) h2[r][c] = tanhf(acc[r] + bb);
    } else {
        const int c = tid - HH;
        float acc[RPB];
#pragma unroll
        for (int r = 0; r < RPB; ++r) acc[r] = 0.f;
        for (int k = 0; k < DD; k += 4) {
            float w0 = cw1[(k + 0) * HH + c];
            float w1 = cw1[(k + 1) * HH + c];
            float w2 = cw1[(k + 2) * HH + c];
            float w3 = cw1[(k + 3) * HH + c];
#pragma unroll
            for (int r = 0; r < RPB; ++r) {
                float4 xv = *(const float4*)&xs[r][k];
                acc[r] += xv.x * w0 + xv.y * w1 + xv.z * w2 + xv.w * w3;
            }
        }
        float bb = cb1[c];
#pragma unroll
        for (int r = 0; r < RPB; ++r) {
            float t = acc[r] + bb;
            hc[r][c] = gelu_exact(t);
        }
    }
    __syncthreads();

    {
        const int wave = tid >> 6, lane = tid & 63;
        float gc = fminf(fmaxf(gcp[0], 0.1f), 2.0f);
        for (int r = wave; r < RPB; r += 4) {
            float f = h2[r][lane] * fw3[lane] + h2[r][lane + 64] * fw3[lane + 64];
            for (int off = 32; off; off >>= 1) f += __shfl_xor(f, off);
            float cpl = hc[r][lane] * cw2[lane] + hc[r][lane + 64] * cw2[lane + 64];
            for (int off = 32; off; off >>= 1) cpl += __shfl_xor(cpl, off);
            float ssum = 0.f, csum = 0.f;
#pragma unroll
            for (int j = 0; j < 4; ++j) {
                int idx = lane + 64 * j;
                float xv = xs[r][idx];
                float fi = (float)idx;
                ssum += xv * sinf(fi);
                csum += xv * cosf(fi);
            }
            for (int off = 32; off; off >>= 1) {
                ssum += __shfl_xor(ssum, off);
                csum += __shfl_xor(csum, off);
            }
            if (lane == 0) {
                int row = base_row + r;
                freq_out[row] = f + fb3[0];
                float sg = sigmoidf(cpl + cb2[0]);
                coup_out[row] = sg;
                cs_ws[row] = sg * gc;
                float ph = atan2f(ssum, csum);
                phases_out[row] = ph;
                pc0f[row] = cosf(ph);
                ps0f[row] = sinf(ph);
            }
        }
    }
}

// ---------------- device-scope grid barrier ---------------------------------
__device__ __forceinline__ void gbar(unsigned* cnt, unsigned* gen, unsigned* mygen) {
    __syncthreads();
    if (threadIdx.x == 0) {
        unsigned arrived = __hip_atomic_fetch_add(cnt, 1u, __ATOMIC_ACQ_REL, __HIP_MEMORY_SCOPE_AGENT);
        if (arrived == NBLK - 1u) {
            __hip_atomic_store(cnt, 0u, __ATOMIC_RELAXED, __HIP_MEMORY_SCOPE_AGENT);
            __hip_atomic_fetch_add(gen, 1u, __ATOMIC_ACQ_REL, __HIP_MEMORY_SCOPE_AGENT);
        } else {
            while (__hip_atomic_load(gen, __ATOMIC_ACQUIRE, __HIP_MEMORY_SCOPE_AGENT) == *mygen)
                __builtin_amdgcn_s_sleep(2);
        }
        *mygen += 1u;
    }
    __syncthreads();
}

// ---------------- persistent Kuramoto: lo-plane in NAMED registers ----------
// Wave w of block b owns 4 full rows 32b+4w..+3. The 32 lo-plane uint4s are
// individually named SSA values (no alloca -> cannot be demoted to scratch).
// Nibble plane (32 MiB total, 4 MiB/XCD = L2-sized) is re-read each step.
// FP accumulation order identical to round 6 (passing) kernel.
#define AV(r, i) aA##r##_##i
#define DECL_A(r) uint4 AV(r,0), AV(r,1), AV(r,2), AV(r,3), AV(r,4), AV(r,5), AV(r,6), AV(r,7)
#define LOADROW(r) do { \
    const uint4* lop = (const uint4*)(Ap + (size_t)(32 * b + 4 * w + (r)) * ROWB); \
    AV(r,0) = lop[0 * 64 + l]; AV(r,1) = lop[1 * 64 + l]; \
    AV(r,2) = lop[2 * 64 + l]; AV(r,3) = lop[3 * 64 + l]; \
    AV(r,4) = lop[4 * 64 + l]; AV(r,5) = lop[5 * 64 + l]; \
    AV(r,6) = lop[6 * 64 + l]; AV(r,7) = lop[7 * 64 + l]; \
} while (0)
#define ROWSTEP(r, it) do { \
    uint2 nb = nbp[r][(it) * 64 + l]; \
    unsigned hea = nb.x & 0x0F0F0F0Fu, hoa = (nb.x >> 4) & 0x0F0F0F0Fu; \
    unsigned heb = nb.y & 0x0F0F0F0Fu, hob = (nb.y >> 4) & 0x0F0F0F0Fu; \
    acc4(AV(r,it).x, hea, hoa, 0, c0, s0, lac[r], las[r]); \
    acc4(AV(r,it).y, hea, hoa, 2, c1, s1, lac[r], las[r]); \
    acc4(AV(r,it).z, heb, hob, 0, c2, s2, lac[r], las[r]); \
    acc4(AV(r,it).w, heb, hob, 2, c3, s3, lac[r], las[r]); \
} while (0)
#define ITSTEP(it) do { \
    const int base_ = l + 256 * (it); \
    float4 c0 = Pc[base_], c1 = Pc[base_ + 64], c2 = Pc[base_ + 128], c3 = Pc[base_ + 192]; \
    float4 s0 = Ps[base_], s1 = Ps[base_ + 64], s2 = Ps[base_ + 128], s3 = Ps[base_ + 192]; \
    ROWSTEP(0, it); ROWSTEP(1, it); ROWSTEP(2, it); ROWSTEP(3, it); \
} while (0)

__global__ __launch_bounds__(512)
__attribute__((amdgpu_waves_per_eu(2, 2)))
void kuramoto_kernel(
    const unsigned char* __restrict__ Ap, const float* __restrict__ freq,
    const float* __restrict__ csv, float* __restrict__ phases,
    float* __restrict__ vA, float* __restrict__ vB,
    unsigned* __restrict__ bar)
{
    __shared__ float vc[NN];        // 32 KB cos
    __shared__ float vs[NN];        // 32 KB sin
    __shared__ float part[8][8];
    const int tid = threadIdx.x, l = tid & 63, w = tid >> 6;
    const int b = blockIdx.x;

    // nibble-plane base pointers (literal-indexed pointer array -> SROA)
    const uint2* nbp[4];
#pragma unroll
    for (int r = 0; r < 4; ++r)
        nbp[r] = (const uint2*)(Ap + (size_t)(32 * b + 4 * w + r) * ROWB + 8192);

    // ---- lo-plane into 32 named uint4 registers (128 VGPRs) ----
    DECL_A(0); DECL_A(1); DECL_A(2); DECL_A(3);
    LOADROW(0); LOADROW(1); LOADROW(2); LOADROW(3);

    float myphase = 0.f, myfreq = 0.f, mycs = 0.f;
    if (tid < 32) {
        int R = 32 * b + tid;
        myphase = phases[R];
        myfreq = freq[R];
        mycs = csv[R];
    }
    unsigned mygen = 0;

    for (int t = 0; t < 60; ++t) {
        const float* vin = (t & 1) ? vB : vA;
        float* vout = (t & 1) ? vA : vB;
        const unsigned long long* vin8 = (const unsigned long long*)vin;
        // ---- stage cos/sin (16384 f32) to LDS via LLC-coherent loads ----
#pragma unroll
        for (int k = 0; k < 8; ++k) {
            int c4 = tid + 512 * k;   // float4 chunk 0..4095
            unsigned long long d0 = __hip_atomic_load(vin8 + 2 * c4,     __ATOMIC_RELAXED, __HIP_MEMORY_SCOPE_AGENT);
            unsigned long long d1 = __hip_atomic_load(vin8 + 2 * c4 + 1, __ATOMIC_RELAXED, __HIP_MEMORY_SCOPE_AGENT);
            int fi = c4 * 4;
            float* dst = (fi < NN) ? (vc + fi) : (vs + (fi - NN));
            ((unsigned long long*)dst)[0] = d0;
            ((unsigned long long*)dst)[1] = d1;
        }
        __syncthreads();
        // ---- dot products: 4 full rows per wave, round-6 element order ----
        float lac[4], las[4];
#pragma unroll
        for (int r = 0; r < 4; ++r) { lac[r] = 0.f; las[r] = 0.f; }
        const float4* Pc = (const float4*)vc;
        const float4* Ps = (const float4*)vs;
        ITSTEP(0); ITSTEP(1); ITSTEP(2); ITSTEP(3);
        ITSTEP(4); ITSTEP(5); ITSTEP(6); ITSTEP(7);
        // ---- wave butterfly, publish per-row sums ----
#pragma unroll
        for (int r = 0; r < 4; ++r) {
            float c = lac[r], s = las[r];
            for (int off = 32; off; off >>= 1) { c += __shfl_xor(c, off); s += __shfl_xor(s, off); }
            if (l == 0) { part[w][2 * r] = c; part[w][2 * r + 1] = s; }
        }
        __syncthreads();
        // ---- phase update: tid<32, row 32b+tid ----
        if (tid < 32) {
            const float inv = 1.f / 4095.f;
            float c = part[tid >> 2][2 * (tid & 3)] * inv;
            float s = part[tid >> 2][2 * (tid & 3) + 1] * inv;
            float ce = atan2f(s, c + 1e-8f) - myphase;
            float dphi = myfreq + mycs * sinf(ce);
            float pn = myphase + DT_F * dphi;
            pn = fmodf(pn, TWO_PI_F);
            if (pn < 0.f) pn += TWO_PI_F;
            myphase = pn;
            if (t < 59) {
                int R = 32 * b + tid;
                __hip_atomic_store(vout + R,      cosf(pn), __ATOMIC_RELAXED, __HIP_MEMORY_SCOPE_AGENT);
                __hip_atomic_store(vout + NN + R, sinf(pn), __ATOMIC_RELAXED, __HIP_MEMORY_SCOPE_AGENT);
            }
        }
        if (t < 59) gbar(bar, bar + 32, &mygen);
    }
    if (tid < 32) phases[32 * b + tid] = myphase;
}

// ---------------- fp32 fallback step (ws too small) -------------------------
#define FSROWS 8
#define CHUNK 4096
__global__ __launch_bounds__(256) void step_kernel(
    const float* __restrict__ A,
    const float* __restrict__ pc_in, const float* __restrict__ ps_in,
    const float* __restrict__ freq, const float* __restrict__ cs,
    float* __restrict__ phases,
    float* __restrict__ pc_out, float* __restrict__ ps_out)
{
    __shared__ float pcs[CHUNK];
    __shared__ float pss[CHUNK];
    const int tid = threadIdx.x, lane = tid & 63, wave = tid >> 6;
    const int row0 = blockIdx.x * FSROWS + wave * (FSROWS / 4);
    float accC[FSROWS / 4], accS[FSROWS / 4];
#pragma unroll
    for (int rr = 0; rr < FSROWS / 4; ++rr) { accC[rr] = 0.f; accS[rr] = 0.f; }
    for (int ch = 0; ch < NN / CHUNK; ++ch) {
        const float4* pcg = (const float4*)(pc_in + ch * CHUNK);
        const float4* psg = (const float4*)(ps_in + ch * CHUNK);
        for (int i = tid; i < CHUNK / 4; i += 256) {
            ((float4*)pcs)[i] = pcg[i];
            ((float4*)pss)[i] = psg[i];
        }
        __syncthreads();
#pragma unroll
        for (int rr = 0; rr < FSROWS / 4; ++rr) {
            const float4* Ar = (const float4*)(A + (size_t)(row0 + rr) * NN + ch * CHUNK);
            float lac = 0.f, las = 0.f;
#pragma unroll 4
            for (int it = 0; it < CHUNK / 256; ++it) {
                int c4 = it * 64 + lane;
                float4 a = Ar[c4];
                float4 c = ((const float4*)pcs)[c4];
                float4 s = ((const float4*)pss)[c4];
                lac += a.x * c.x + a.y * c.y + a.z * c.z + a.w * c.w;
                las += a.x * s.x + a.y * s.y + a.z * s.z + a.w * s.w;
            }
            accC[rr] += lac;
            accS[rr] += las;
        }
        __syncthreads();
    }
#pragma unroll
    for (int rr = 0; rr < FSROWS / 4; ++rr) {
        float c = accC[rr], s = accS[rr];
        for (int off = 32; off; off >>= 1) {
            c += __shfl_xor(c, off);
            s += __shfl_xor(s, off);
        }
        if (lane == 0) {
            int row = row0 + rr;
            float ph = phases[row];
            float ce = atan2f(s, c + 1e-8f) - ph;
            float dphi = freq[row] + cs[row] * sinf(ce);
            float pn = fmodf(ph + DT_F * dphi, TWO_PI_F);
            if (pn < 0.f) pn += TWO_PI_F;
            phases[row] = pn;
            pc_out[row] = cosf(pn);
            ps_out[row] = sinf(pn);
        }
    }
}

// ---------------- post: sync_input, sync MLP -> desync ----------------------
#define SD 260
#define SDP 264
__global__ __launch_bounds__(256) void post_kernel(
    const float* __restrict__ x, const float* __restrict__ phases,
    const float* __restrict__ sw1, const float* __restrict__ sb1,
    const float* __restrict__ slng, const float* __restrict__ slnb,
    const float* __restrict__ sw2, const float* __restrict__ sb2,
    const float* __restrict__ sw3, const float* __restrict__ sb3,
    float* __restrict__ sync_out, float* __restrict__ desync_out)
{
    __shared__ float xs[RPB][SDP];
    __shared__ float h1[RPB][DD];
    __shared__ float h2[RPB][HH];
    const int tid = threadIdx.x;
    const int base_row = blockIdx.x * RPB;

    for (int i = tid; i < RPB * DD / 4; i += 256) {
        int r = i / (DD / 4), c4 = i % (DD / 4);
        *(float4*)&xs[r][c4 * 4] = ((const float4*)(x + (size_t)(base_row + r) * DD))[c4];
    }
    if (tid < RPB) {
        float p = phases[base_row + tid];
        xs[tid][256] = cosf(p);
        xs[tid][257] = sinf(p);
        xs[tid][258] = cosf(2.f * p);
        xs[tid][259] = sinf(2.f * p);
    }
    __syncthreads();

    for (int i = tid; i < RPB * SD; i += 256) {
        int r = i / SD, c = i % SD;
        sync_out[(size_t)(base_row + r) * SD + c] = xs[r][c];
    }

    {
        float acc[RPB];
#pragma unroll
        for (int r = 0; r < RPB; ++r) acc[r] = 0.f;
        const int c = tid;
        for (int k = 0; k < SD; k += 4) {
            float w0 = sw1[(k + 0) * DD + c];
            float w1 = sw1[(k + 1) * DD + c];
            float w2 = sw1[(k + 2) * DD + c];
            float w3 = sw1[(k + 3) * DD + c];
#pragma unroll
            for (int r = 0; r < RPB; ++r) {
                float4 xv = *(const float4*)&xs[r][k];
                acc[r] += xv.x * w0 + xv.y * w1 + xv.z * w2 + xv.w * w3;
            }
        }
        float bb = sb1[c];
#pragma unroll
        for (int r = 0; r < RPB; ++r) h1[r][c] = acc[r] + bb;
    }
    __syncthreads();

    {
        const int wave = tid >> 6, lane = tid & 63;
        for (int r = wave; r < RPB; r += 4) {
            float v0 = h1[r][lane], v1 = h1[r][lane + 64], v2 = h1[r][lane + 128], v3 = h1[r][lane + 192];
            float s = v0 + v1 + v2 + v3;
            for (int off = 32; off; off >>= 1) s += __shfl_xor(s, off);
            float m = s * (1.f / DD);
            float d0 = v0 - m, d1 = v1 - m, d2 = v2 - m, d3 = v3 - m;
            float q = d0 * d0 + d1 * d1 + d2 * d2 + d3 * d3;
            for (int off = 32; off; off >>= 1) q += __shfl_xor(q, off);
            float rstd = rsqrtf(q * (1.f / DD) + 1e-5f);
            h1[r][lane]       = gelu_exact(d0 * rstd * slng[lane]       + slnb[lane]);
            h1[r][lane + 64]  = gelu_exact(d1 * rstd * slng[lane + 64]  + slnb[lane + 64]);
            h1[r][lane + 128] = gelu_exact(d2 * rstd * slng[lane + 128] + slnb[lane + 128]);
            h1[r][lane + 192] = gelu_exact(d3 * rstd * slng[lane + 192] + slnb[lane + 192]);
        }
    }
    __syncthreads();

    if (tid < HH) {
        const int c = tid;
        float acc[RPB];
#pragma unroll
        for (int r = 0; r < RPB; ++r) acc[r] = 0.f;
        for (int k = 0; k < DD; k += 4) {
            float w0 = sw2[(k + 0) * HH + c];
            float w1 = sw2[(k + 1) * HH + c];
            float w2 = sw2[(k + 2) * HH + c];
            float w3 = sw2[(k + 3) * HH + c];
#pragma unroll
            for (int r = 0; r < RPB; ++r) {
                float4 xv = *(const float4*)&h1[r][k];
                acc[r] += xv.x * w0 + xv.y * w1 + xv.z * w2 + xv.w * w3;
            }
        }
        float bb = sb2[c];
#pragma unroll
        for (int r = 0; r < RPB; ++r) h2[r][c] = gelu_exact(acc[r] + bb);
    }
    __syncthreads();

    {
        const int wave = tid >> 6, lane = tid & 63;
        for (int r = wave; r < RPB; r += 4) {
            float t = h2[r][lane] * sw3[lane] + h2[r][lane + 64] * sw3[lane + 64];
            for (int off = 32; off; off >>= 1) t += __shfl_xor(t, off);
            if (lane == 0) desync_out[base_row + r] = sigmoidf(t + sb3[0]);
        }
    }
}

// ---------------- global scalar reductions ---------------------------------
__global__ __launch_bounds__(1024) void reduce_kernel(
    const float* __restrict__ phases,
    float* __restrict__ order_out, float* __restrict__ coh_out)
{
    __shared__ double red[16][4];
    const int tid = threadIdx.x;
    double sc = 0, ss = 0, sp = 0, spp = 0;
    for (int i = tid; i < NN; i += 1024) {
        float p = phases[i];
        sc += (double)cosf(p);
        ss += (double)sinf(p);
        sp += (double)p;
        spp += (double)p * (double)p;
    }
    const int lane = tid & 63, wave = tid >> 6;
    for (int off = 32; off; off >>= 1) {
        sc += __shfl_xor(sc, off);
        ss += __shfl_xor(ss, off);
        sp += __shfl_xor(sp, off);
        spp += __shfl_xor(spp, off);
    }
    if (lane == 0) { red[wave][0] = sc; red[wave][1] = ss; red[wave][2] = sp; red[wave][3] = spp; }
    __syncthreads();
    if (tid == 0) {
        sc = 0; ss = 0; sp = 0; spp = 0;
        for (int w = 0; w < 16; ++w) { sc += red[w][0]; ss += red[w][1]; sp += red[w][2]; spp += red[w][3]; }
        double mc = sc / NN, ms = ss / NN;
        order_out[0] = (float)sqrt(mc * mc + ms * ms);
        double var = (spp - sp * sp / NN) / (NN - 1);
        if (var < 0) var = 0;
        coh_out[0] = (float)(1.0 / (1.0 + sqrt(var)));
    }
}

extern "C" void kernel_launch(void* const* d_in, const int* in_sizes, int n_in,
                              void* d_out, int out_size, void* d_ws, size_t ws_size,
                              hipStream_t stream) {
    const float* x    = (const float*)d_in[0];
    const float* A    = (const float*)d_in[1];
    const float* fw1  = (const float*)d_in[2];
    const float* fb1  = (const float*)d_in[3];
    const float* flng = (const float*)d_in[4];
    const float* flnb = (const float*)d_in[5];
    const float* fw2  = (const float*)d_in[6];
    const float* fb2  = (const float*)d_in[7];
    const float* fw3  = (const float*)d_in[8];
    const float* fb3  = (const float*)d_in[9];
    const float* cw1  = (const float*)d_in[10];
    const float* cb1  = (const float*)d_in[11];
    const float* cw2  = (const float*)d_in[12];
    const float* cb2  = (const float*)d_in[13];
    const float* sw1  = (const float*)d_in[14];
    const float* sb1  = (const float*)d_in[15];
    const float* slng = (const float*)d_in[16];
    const float* slnb = (const float*)d_in[17];
    const float* sw2  = (const float*)d_in[18];
    const float* sb2  = (const float*)d_in[19];
    const float* sw3  = (const float*)d_in[20];
    const float* sb3  = (const float*)d_in[21];
    const float* gcp  = (const float*)d_in[22];

    float* out    = (float*)d_out;
    float* desync = out;                    // 8192
    float* order  = out + 8192;             // 1
    float* phases = out + 8193;             // 8192
    float* freqo  = out + 16385;            // 8192
    float* coupo  = out + 24577;            // 8192
    float* synco  = out + 32769;            // 8192*260
    float* coh    = out + 2162689;          // 1

    char* wsb = (char*)d_ws;
    unsigned* bar = (unsigned*)(wsb + 0);        // 512 B, memset each launch
    float* cs  = (float*)(wsb + 4096);           // 32 KB
    float* vA  = (float*)(wsb + 65536);          // 64 KB [cos|sin]
    float* vB  = (float*)(wsb + 131072);         // 64 KB
    unsigned char* Ap = (unsigned char*)(wsb + 262144);  // 96 MiB packed A

    const bool persistent = ws_size >= (size_t)262144 + (size_t)NN * ROWB;

    if (persistent) {
        hipMemsetAsync(bar, 0, 512, stream);
        convert_pack_kernel<<<NN, 512, 0, stream>>>(A, Ap);
    }
    pre_kernel<<<NN / RPB, 256, 0, stream>>>(x, fw1, fb1, flng, flnb, fw2, fb2, fw3, fb3,
                                             cw1, cb1, cw2, cb2, gcp,
                                             freqo, coupo, cs, phases, vA, vA + NN);
    if (persistent) {
        kuramoto_kernel<<<NBLK, 512, 0, stream>>>(Ap, freqo, cs, phases, vA, vB, bar);
    } else {
        for (int t = 0; t < 60; ++t) {
            const float* pin  = (t & 1) ? vB : vA;
            const float* sin_ = (t & 1) ? vB + NN : vA + NN;
            float* pout = (t & 1) ? vA : vB;
            float* sout = (t & 1) ? vA + NN : vB + NN;
            step_kernel<<<NN / FSROWS, 256, 0, stream>>>(A, pin, sin_, freqo, cs, phases, pout, sout);
        }
    }
    post_kernel<<<NN / RPB, 256, 0, stream>>>(x, phases, sw1, sb1, slng, slnb, sw2, sb2, sw3, sb3,
                                              synco, desync);
    reduce_kernel<<<1, 1024, 0, stream>>>(phases, order, coh);
}